// Round 5
// baseline (226.643 us; speedup 1.0000x reference)
//
#include <hip/hip_runtime.h>

// Q = L @ L^T for 3x3 lower-triangular L packed as 6 floats per item:
// packed order (row,col) = (0,0),(1,0),(1,1),(2,0),(2,1),(2,2) -> a,b,c,d,e,f
// Unique entries: u0=a*a u1=a*b u2=a*d u3=b*b+c*c u4=b*d+c*e u5=d*d+e*e+f*f
// Row-major comps [0..8] -> [u0,u1,u2, u1,u3,u4, u2,u4,u5]
//
// R4 lesson (delta-fit across rounds): kernel ~83us ≈ 3 TB/s, NOT HBM-bound,
// yet no internal pipe (LDS/VALU/divergence) accounts for it. The only
// un-evidenced variable: nontemporal hints added in R3, which bypass L2 —
// while every 6.3-6.5 TB/s reference path (fillBuffer, d2d copy) goes
// through L2. R5 = exact same kernel with nt removed (single-variable A/B).

#define THREADS 256
#define IPB 1024  // items per block: s_in = 24 KB -> 6 blocks/CU

typedef float f4 __attribute__((ext_vector_type(4)));

__global__ __launch_bounds__(THREADS) void chol_to_cov_kernel(
    const float* __restrict__ in, float* __restrict__ out, long long n_items) {
  __shared__ float s_in[IPB * 6];  // 24 KB

  const int tid = threadIdx.x;
  const long long block_base = (long long)blockIdx.x * IPB;

  if (block_base + IPB <= n_items) {
    // ---- global -> LDS: 6 float4/thread, unit lane stride ----
    const f4* __restrict__ in4 = (const f4*)(in + block_base * 6);
    f4* s4 = (f4*)s_in;
#pragma unroll
    for (int k = 0; k < 6; k++) {
      const int idx = tid + k * THREADS;
      s4[idx] = in4[idx];
    }
    __syncthreads();

    // ---- compute + store: 9 float4/thread, unit lane stride ----
    f4* __restrict__ out4 = (f4*)(out + block_base * 9);
#pragma unroll
    for (int k = 0; k < 9; k++) {
      const unsigned g = (unsigned)tid + k * THREADS;  // < 2304
      const unsigned e = 4u * g;                       // first element index
      const unsigned item = e / 9u;                    // magic-mul
      const unsigned r = e - 9u * item;
      unsigned i1 = item + 1u;
      if (i1 > IPB - 1u) i1 = IPB - 1u;  // clamp (r>=6 never hits last item)

      const float* p0 = s_in + item * 6;
      const float a = p0[0], b = p0[1], c = p0[2];
      const float d = p0[3], e0 = p0[4], f = p0[5];
      const float u0 = a * a;
      const float u1 = a * b;
      const float u2 = a * d;
      const float u3 = b * b + c * c;
      const float u4 = b * d + c * e0;
      const float u5 = d * d + e0 * e0 + f * f;

      const float* p1 = s_in + i1 * 6;
      const float a1 = p1[0], b1 = p1[1], d1 = p1[3];
      const float v0 = a1 * a1;
      const float v1 = a1 * b1;
      const float v2 = a1 * d1;

      f4 o;
      switch (r) {
        case 0: o = (f4){u0, u1, u2, u1}; break;
        case 1: o = (f4){u1, u2, u1, u3}; break;
        case 2: o = (f4){u2, u1, u3, u4}; break;
        case 3: o = (f4){u1, u3, u4, u2}; break;
        case 4: o = (f4){u3, u4, u2, u4}; break;
        case 5: o = (f4){u4, u2, u4, u5}; break;
        case 6: o = (f4){u2, u4, u5, v0}; break;
        case 7: o = (f4){u4, u5, v0, v1}; break;
        default: o = (f4){u5, v0, v1, v2}; break;
      }
      out4[g] = o;
    }
  } else {
    // ---- guarded tail path (unused at 4096*1024 items) ----
    for (long long it = block_base + tid; it < n_items; it += THREADS) {
      const float a = in[it * 6 + 0];
      const float b = in[it * 6 + 1];
      const float c = in[it * 6 + 2];
      const float d = in[it * 6 + 3];
      const float e = in[it * 6 + 4];
      const float f = in[it * 6 + 5];
      float* o = out + it * 9;
      o[0] = a * a;
      o[1] = a * b;
      o[2] = a * d;
      o[3] = a * b;
      o[4] = b * b + c * c;
      o[5] = b * d + c * e;
      o[6] = a * d;
      o[7] = b * d + c * e;
      o[8] = d * d + e * e + f * f;
    }
  }
}

extern "C" void kernel_launch(void* const* d_in, const int* in_sizes, int n_in,
                              void* d_out, int out_size, void* d_ws,
                              size_t ws_size, hipStream_t stream) {
  const float* in = (const float*)d_in[0];
  float* out = (float*)d_out;
  const long long n_items = (long long)in_sizes[0] / 6;  // 4,194,304
  const long long grid = (n_items + IPB - 1) / IPB;      // 4096
  chol_to_cov_kernel<<<(int)grid, THREADS, 0, stream>>>(in, out, n_items);
}